// Round 2
// baseline (446.381 us; speedup 1.0000x reference)
//
#include <hip/hip_runtime.h>
#include <hip/hip_bf16.h>

// AWQ int4 GEMM: out[M,N] = x[M,K] @ dequant(qweight,qzeros,scales)
// M=2048 K=4096 N=11008 G=128.
// Fused dequant + bf16 MFMA GEMM, 128x128 tile, BK=64, 4 waves.
// This round: linear PADDED LDS (no XOR swizzle), reference-exact dequant.

#define MDIM 2048
#define KDIM 4096
#define NDIM 11008
#define NPC  (NDIM / 8)   // 1376 packed columns

#define BM 128
#define BN 128
#define BK 64
#define NT (KDIM / BK)    // 64 K-tiles
#define LDW 9             // slots per row: 8 data (16B each) + 1 pad

typedef __attribute__((ext_vector_type(8))) short short8;   // 8 bf16 = 4 VGPR
typedef __attribute__((ext_vector_type(4))) float f32x4;    // MFMA acc

__device__ __forceinline__ unsigned short f2bf(float f) {
    union { float f; unsigned u; } v; v.f = f;
    unsigned r = v.u + 0x7FFFu + ((v.u >> 16) & 1u);  // RNE
    return (unsigned short)(r >> 16);
}

__global__ __launch_bounds__(256, 2)
void awq_gemm(const float* __restrict__ x,
              const int* __restrict__ qw,
              const unsigned* __restrict__ qz,
              const float* __restrict__ sc,
              float* __restrict__ out)
{
    // LDS tiles in 16B slots (8 bf16). Row stride LDW=9 slots (144B) to
    // break power-of-2 bank patterns. Slot s of row r holds k in [8s, 8s+8).
    __shared__ short8 As[BM * LDW];   // A: row-major K
    __shared__ short8 Bs[BN * LDW];   // B: N-major, contiguous K per n

    const int t    = threadIdx.x;
    const int lane = t & 63;
    const int wave = t >> 6;
    const int WR   = wave >> 1;   // 2x2 wave grid of 64x64 sub-tiles
    const int WC   = wave & 1;

    const int m0  = blockIdx.y * BM;
    const int n0  = blockIdx.x * BN;
    const int pc0 = n0 >> 3;

    // A staging: thread covers rows {arow, arow+64}, k-chunk akq*16 (16 floats)
    const int arow = t >> 2;
    const int akq  = t & 3;
    // B staging: thread covers k rows bkq*4..+3, packed col bpc (8 n-cols)
    const int bkq = t & 15;
    const int bpc = t >> 4;

    const float* xp  = x + (size_t)(m0 + arow) * KDIM + akq * 16;
    const float* xp2 = xp + (size_t)64 * KDIM;
    const int*   qwp = qw + (size_t)(bkq * 4) * NPC + pc0 + bpc;

    const int SH[8] = {0, 16, 4, 20, 8, 24, 12, 28};  // AWQ inverse-interleave shifts

    f32x4 acc[4][4];
    #pragma unroll
    for (int i = 0; i < 4; ++i)
        #pragma unroll
        for (int j = 0; j < 4; ++j)
            acc[i][j] = (f32x4){0.f, 0.f, 0.f, 0.f};

    // prefetch registers
    float4   ra[8];
    int      rb[4];
    unsigned rz;
    float4   rs0, rs1;

#define LOADREGS(K0) do {                                                   \
    const float* ap  = xp  + (K0);                                          \
    const float* ap2 = xp2 + (K0);                                          \
    ra[0] = *(const float4*)(ap);      ra[1] = *(const float4*)(ap + 4);    \
    ra[2] = *(const float4*)(ap + 8);  ra[3] = *(const float4*)(ap + 12);   \
    ra[4] = *(const float4*)(ap2);     ra[5] = *(const float4*)(ap2 + 4);   \
    ra[6] = *(const float4*)(ap2 + 8); ra[7] = *(const float4*)(ap2 + 12);  \
    const int* bp = qwp + (size_t)(K0) * NPC;                               \
    rb[0] = bp[0]; rb[1] = bp[NPC]; rb[2] = bp[2 * NPC]; rb[3] = bp[3 * NPC]; \
    const int g = (K0) >> 7; /* group = k/128 (BK=64 divides G=128) */      \
    rz = qz[(size_t)g * NPC + pc0 + bpc];                                   \
    const float* sp = sc + (size_t)g * NDIM + n0 + bpc * 8;                 \
    rs0 = *(const float4*)sp; rs1 = *(const float4*)(sp + 4);               \
} while (0)

    LOADREGS(0);

    for (int tt = 0; tt < NT; ++tt) {
        __syncthreads();   // previous compute done; LDS free to overwrite

        // ---- A: fp32 -> bf16, write 2 rows x 16 floats (2 slots each) ----
        #pragma unroll
        for (int p = 0; p < 2; ++p) {
            const int row = arow + p * 64;
            #pragma unroll
            for (int c = 0; c < 2; ++c) {
                const float4 f0 = ra[p * 4 + c * 2];
                const float4 f1 = ra[p * 4 + c * 2 + 1];
                uint4 w;
                w.x = f2bf(f0.x) | ((unsigned)f2bf(f0.y) << 16);
                w.y = f2bf(f0.z) | ((unsigned)f2bf(f0.w) << 16);
                w.z = f2bf(f1.x) | ((unsigned)f2bf(f1.y) << 16);
                w.w = f2bf(f1.z) | ((unsigned)f2bf(f1.w) << 16);
                const int slot = akq * 2 + c;                 // linear, no swizzle
                *(uint4*)&As[row * LDW + slot] = w;
            }
        }

        // ---- B: unpack int4, dequant (q - z) * s -> bf16, N-major ----
        {
            const float sarr[8] = {rs0.x, rs0.y, rs0.z, rs0.w,
                                   rs1.x, rs1.y, rs1.z, rs1.w};
            int zv[8];
            #pragma unroll
            for (int m = 0; m < 8; ++m)
                zv[m] = (int)((rz >> SH[m]) & 0xFu);
            #pragma unroll
            for (int m = 0; m < 8; ++m) {
                const int n = bpc * 8 + m;
                unsigned short wv[4];
                #pragma unroll
                for (int r = 0; r < 4; ++r) {
                    const int q = (int)(((unsigned)rb[r] >> SH[m]) & 0xFu);
                    wv[r] = f2bf((float)(q - zv[m]) * sarr[m]);   // exact ref formula
                }
                uint2 pk;
                pk.x = wv[0] | ((unsigned)wv[1] << 16);
                pk.y = wv[2] | ((unsigned)wv[3] << 16);
                const int slot = bkq >> 1;                    // linear, no swizzle
                ((uint2*)&Bs[n * LDW + slot])[bkq & 1] = pk;
            }
        }

        __syncthreads();

        // ---- prefetch next tile's globals (overlaps with MFMA below) ----
        if (tt + 1 < NT) { LOADREGS((tt + 1) * BK); }

        // ---- compute: 2 K-substeps x 4x4 fragments ----
        #pragma unroll
        for (int ks = 0; ks < 2; ++ks) {
            short8 af[4], bfr[4];
            const int kk   = ks * 32 + (lane >> 4) * 8;
            const int slin = kk >> 3;
            #pragma unroll
            for (int i = 0; i < 4; ++i) {
                const int row = WR * 64 + i * 16 + (lane & 15);
                af[i] = As[row * LDW + slin];
            }
            #pragma unroll
            for (int j = 0; j < 4; ++j) {
                const int n = WC * 64 + j * 16 + (lane & 15);
                bfr[j] = Bs[n * LDW + slin];
            }
            #pragma unroll
            for (int i = 0; i < 4; ++i)
                #pragma unroll
                for (int j = 0; j < 4; ++j)
                    acc[i][j] = __builtin_amdgcn_mfma_f32_16x16x32_bf16(
                        af[i], bfr[j], acc[i][j], 0, 0, 0);
        }
    }

    // ---- epilogue: C/D layout col=lane&15, row=(lane>>4)*4+e ----
    const int crow = (lane >> 4) * 4;
    const int ccol = lane & 15;
    #pragma unroll
    for (int i = 0; i < 4; ++i) {
        #pragma unroll
        for (int j = 0; j < 4; ++j) {
            const size_t base =
                (size_t)(m0 + WR * 64 + i * 16 + crow) * NDIM +
                (n0 + WC * 64 + j * 16 + ccol);
            #pragma unroll
            for (int e = 0; e < 4; ++e)
                out[base + (size_t)e * NDIM] = acc[i][j][e];
        }
    }
#undef LOADREGS
}

extern "C" void kernel_launch(void* const* d_in, const int* in_sizes, int n_in,
                              void* d_out, int out_size, void* d_ws, size_t ws_size,
                              hipStream_t stream) {
    const float*    x  = (const float*)d_in[0];
    const int*      qw = (const int*)d_in[1];
    const unsigned* qz = (const unsigned*)d_in[2];
    const float*    sc = (const float*)d_in[3];
    float* out = (float*)d_out;

    dim3 grid(NDIM / BN, MDIM / BM);   // 86 x 16
    awq_gemm<<<grid, 256, 0, stream>>>(x, qw, qz, sc, out);
}

// Round 4
// 243.093 us; speedup vs baseline: 1.8363x; 1.8363x over previous
//
#include <hip/hip_runtime.h>
#include <hip/hip_bf16.h>

// AWQ int4 GEMM: out[M,N] = x[M,K] @ dequant(qweight,qzeros,scales)
// M=2048 K=4096 N=11008 G=128.
// f16 MFMA pipeline: pk-math dequant, 256x128 tile, 8 waves, BK=64.
// A-path: x pre-converted to f16 LDS-image in d_ws -> global_load_lds (if ws fits).

#define MDIM 2048
#define KDIM 4096
#define NDIM 11008
#define NPC  1376          // N/8 packed columns
#define BM 256
#define BN 128
#define BK 64
#define NT (KDIM / BK)     // 64

typedef _Float16 half8  __attribute__((ext_vector_type(8)));
typedef _Float16 half2v __attribute__((ext_vector_type(2)));
typedef __fp16   fp16x2n __attribute__((ext_vector_type(2)));  // cvt_pkrtz native type
typedef float    f32x4  __attribute__((ext_vector_type(4)));

__device__ __forceinline__ half2v u2h(unsigned u) { union { unsigned u; half2v h; } v; v.u = u; return v.h; }
__device__ __forceinline__ unsigned h2u(half2v h) { union { unsigned u; half2v h; } v; v.h = h; return v.u; }
__device__ __forceinline__ unsigned pkrtz(float a, float b) {
    union { fp16x2n h; unsigned u; } v;
    v.h = __builtin_amdgcn_cvt_pkrtz(a, b);
    return v.u;
}

// ---------------- pre-kernel: x fp32 -> f16 tile-images in ws ----------------
// image layout per (mb,kt): [r 0..255][slot' = s^(r&7)][8 half] == 32KB LDS image
__global__ __launch_bounds__(256) void xconv(const float* __restrict__ x,
                                             _Float16* __restrict__ xi) {
    const int id = blockIdx.x * 256 + threadIdx.x;   // 1,048,576 total
    const int s  = id & 7;
    const int r  = (id >> 3) & 255;
    const int kt = (id >> 11) & 63;
    const int mb = id >> 17;
    const float* src = x + (size_t)(mb * 256 + r) * KDIM + kt * 64 + s * 8;
    const float4 f0 = *(const float4*)src;
    const float4 f1 = *(const float4*)(src + 4);
    half8 h;
    h[0] = (_Float16)f0.x; h[1] = (_Float16)f0.y; h[2] = (_Float16)f0.z; h[3] = (_Float16)f0.w;
    h[4] = (_Float16)f1.x; h[5] = (_Float16)f1.y; h[6] = (_Float16)f1.z; h[7] = (_Float16)f1.w;
    const size_t off = ((size_t)(mb * 64 + kt) * 256 + r) * 64 + (size_t)((s ^ (r & 7)) * 8);
    *(half8*)(xi + off) = h;
}

// ---------------- main kernel ----------------
template <bool XWS>
__global__ __launch_bounds__(512, 4)
void awq_gemm(const float* __restrict__ x,
              const _Float16* __restrict__ xi,
              const int* __restrict__ qw,
              const unsigned* __restrict__ qz,
              const float* __restrict__ sc,
              float* __restrict__ out)
{
    __shared__ _Float16 As[BM * BK];   // 32KB, [row][k], 16B-granule swz ^ (row&7)
    __shared__ _Float16 Bs[BN * BK];   // 16KB, [n][k],   granule swz ^ ((n&7)^((n>>3)&7))

    const int t    = threadIdx.x;
    const int lane = t & 63;
    const int wave = t >> 6;           // 0..7
    const int WR   = wave >> 1;        // 0..3  (64-row band)
    const int WC   = wave & 1;         // 0..1  (64-col band)

    const int mb  = blockIdx.y;
    const int m0  = mb * BM;
    const int n0  = blockIdx.x * BN;
    const int pc0 = n0 >> 3;

    // B staging assignment: bpc = n-packed-col (16), bkp = k-pair (32)
    const int bpc = t & 15;
    const int bkp = t >> 4;
    const int*      qwp = qw + (size_t)(2 * bkp) * NPC + pc0 + bpc;
    const unsigned* qzp = qz + pc0 + bpc;
    const float*    scp = sc + n0 + bpc * 8;

    // A fallback staging: row ar, k-half ak (32 floats)
    const int ar = t >> 1;
    const int ak = (t & 1) * 32;
    const float* xp = x + (size_t)(m0 + ar) * KDIM + ak;

    f32x4 acc[4][4];
    #pragma unroll
    for (int i = 0; i < 4; ++i)
        #pragma unroll
        for (int j = 0; j < 4; ++j)
            acc[i][j] = (f32x4){0.f, 0.f, 0.f, 0.f};

    // prefetch registers
    unsigned rw0, rw1, rz;
    float4   rs0, rs1;
    float4   ra[8];   // fallback only

#define LOADB(TT) do {                                                        \
    const int* bp = qwp + (size_t)(TT) * BK * NPC;                            \
    rw0 = (unsigned)bp[0]; rw1 = (unsigned)bp[NPC];                           \
    rz  = qzp[(size_t)((TT) >> 1) * NPC];                                     \
    const float* sp = scp + (size_t)((TT) >> 1) * NDIM;                       \
    rs0 = *(const float4*)sp; rs1 = *(const float4*)(sp + 4);                 \
} while (0)

#define LOADA(TT) do {                                                        \
    const float* ap = xp + (size_t)(TT) * BK;                                 \
    ra[0]=*(const float4*)(ap);    ra[1]=*(const float4*)(ap+4);              \
    ra[2]=*(const float4*)(ap+8);  ra[3]=*(const float4*)(ap+12);             \
    ra[4]=*(const float4*)(ap+16); ra[5]=*(const float4*)(ap+20);             \
    ra[6]=*(const float4*)(ap+24); ra[7]=*(const float4*)(ap+28);             \
} while (0)

    LOADB(0);
    if (!XWS) LOADA(0);

    for (int tt = 0; tt < NT; ++tt) {
        __syncthreads();   // all waves done reading LDS of previous tile

        // ---- A staging ----
        if (XWS) {
            // direct HBM(f16 image) -> LDS, image already swizzled
            const _Float16* img = xi + ((size_t)(mb * NT + tt) * 16384);
            #pragma unroll
            for (int c = 0; c < 4; ++c) {
                const _Float16* gsrc = img + (size_t)(c * 4096 + wave * 512 + lane * 8);
                __builtin_amdgcn_global_load_lds(
                    (const __attribute__((address_space(1))) void*)gsrc,
                    (__attribute__((address_space(3))) void*)((char*)As + wave * 1024 + c * 8192),
                    16, 0, 0);
            }
        } else {
            #pragma unroll
            for (int c = 0; c < 2; ++c) {
                const float4 f0 = ra[c * 4 + 0], f1 = ra[c * 4 + 1];
                const float4 f2 = ra[c * 4 + 2], f3 = ra[c * 4 + 3];
                uint4 w0, w1;
                w0.x = pkrtz(f0.x, f0.y); w0.y = pkrtz(f0.z, f0.w);
                w0.z = pkrtz(f1.x, f1.y); w0.w = pkrtz(f1.z, f1.w);
                w1.x = pkrtz(f2.x, f2.y); w1.y = pkrtz(f2.z, f2.w);
                w1.z = pkrtz(f3.x, f3.y); w1.w = pkrtz(f3.z, f3.w);
                const int s0 = (ak >> 3) + c * 2;
                *(uint4*)((char*)As + ar * 128 + ((s0 ^ (ar & 7)) * 16))       = w0;
                *(uint4*)((char*)As + ar * 128 + (((s0 + 1) ^ (ar & 7)) * 16)) = w1;
            }
        }

        // ---- B staging: unpack + pk-dequant + perm-transpose ----
        {
            // zeros -> packed fp16(1024+z) per n-pair
            unsigned zh[4], sh[4];
            zh[0] = (rz & 0x000F000Fu) | 0x64006400u;
            zh[1] = ((rz >> 4)  & 0x000F000Fu) | 0x64006400u;
            zh[2] = ((rz >> 8)  & 0x000F000Fu) | 0x64006400u;
            zh[3] = ((rz >> 12) & 0x000F000Fu) | 0x64006400u;
            {
                half2v s01; s01[0] = (_Float16)rs0.x; s01[1] = (_Float16)rs0.y; sh[0] = h2u(s01);
                half2v s23; s23[0] = (_Float16)rs0.z; s23[1] = (_Float16)rs0.w; sh[1] = h2u(s23);
                half2v s45; s45[0] = (_Float16)rs1.x; s45[1] = (_Float16)rs1.y; sh[2] = h2u(s45);
                half2v s67; s67[0] = (_Float16)rs1.z; s67[1] = (_Float16)rs1.w; sh[3] = h2u(s67);
            }
            unsigned dq0[4], dq1[4];   // dequantized n-pair dwords, k and k+1
            #pragma unroll
            for (int p = 0; p < 4; ++p) {
                const unsigned q0 = ((rw0 >> (4 * p)) & 0x000F000Fu) | 0x64006400u;
                const unsigned q1 = ((rw1 >> (4 * p)) & 0x000F000Fu) | 0x64006400u;
                dq0[p] = h2u((u2h(q0) - u2h(zh[p])) * u2h(sh[p]));
                dq1[p] = h2u((u2h(q1) - u2h(zh[p])) * u2h(sh[p]));
            }
            const int kslot = bkp >> 2;            // 16B granule along k
            const int ksub  = (bkp & 3) * 4;       // dword within granule
            #pragma unroll
            for (int p = 0; p < 4; ++p) {
                const unsigned lo = __builtin_amdgcn_perm(dq1[p], dq0[p], 0x05040100u); // n even, (k,k+1)
                const unsigned hi = __builtin_amdgcn_perm(dq1[p], dq0[p], 0x07060302u); // n odd
                const int ne = bpc * 8 + 2 * p;
                const int no = ne + 1;
                const int swe = (ne & 7) ^ ((ne >> 3) & 7);
                const int swo = (no & 7) ^ ((no >> 3) & 7);
                *(unsigned*)((char*)Bs + ne * 128 + ((kslot ^ swe) * 16) + ksub) = lo;
                *(unsigned*)((char*)Bs + no * 128 + ((kslot ^ swo) * 16) + ksub) = hi;
            }
        }

        __syncthreads();   // drains global_load_lds (vmcnt) + ds writes

        // ---- prefetch next tile's globals (overlap with MFMA) ----
        if (tt + 1 < NT) { LOADB(tt + 1); if (!XWS) LOADA(tt + 1); }

        // ---- compute: 2 K-substeps, 4x4 fragments per wave ----
        #pragma unroll
        for (int ks = 0; ks < 2; ++ks) {
            const int slot = ks * 4 + (lane >> 4);
            half8 bfr[4];
            #pragma unroll
            for (int j = 0; j < 4; ++j) {
                const int n = WC * 64 + j * 16 + (lane & 15);
                const int sw = (n & 7) ^ ((n >> 3) & 7);
                bfr[j] = *(const half8*)((char*)Bs + n * 128 + ((slot ^ sw) * 16));
            }
            #pragma unroll
            for (int i = 0; i < 4; ++i) {
                const int row = WR * 64 + i * 16 + (lane & 15);
                const half8 af = *(const half8*)((char*)As + row * 128 + ((slot ^ (row & 7)) * 16));
                #pragma unroll
                for (int j = 0; j < 4; ++j)
                    acc[i][j] = __builtin_amdgcn_mfma_f32_16x16x32_f16(
                        af, bfr[j], acc[i][j], 0, 0, 0);
            }
        }
    }

    // ---- epilogue: C/D layout col=lane&15, row=(lane>>4)*4+e ----
    const int crow = (lane >> 4) * 4;
    const int ccol = lane & 15;
    #pragma unroll
    for (int i = 0; i < 4; ++i) {
        #pragma unroll
        for (int j = 0; j < 4; ++j) {
            const size_t base =
                (size_t)(m0 + WR * 64 + i * 16 + crow) * NDIM +
                (n0 + WC * 64 + j * 16 + ccol);
            #pragma unroll
            for (int e = 0; e < 4; ++e)
                out[base + (size_t)e * NDIM] = acc[i][j][e];
        }
    }
#undef LOADB
#undef LOADA
}

extern "C" void kernel_launch(void* const* d_in, const int* in_sizes, int n_in,
                              void* d_out, int out_size, void* d_ws, size_t ws_size,
                              hipStream_t stream) {
    const float*    x  = (const float*)d_in[0];
    const int*      qw = (const int*)d_in[1];
    const unsigned* qz = (const unsigned*)d_in[2];
    const float*    sc = (const float*)d_in[3];
    float* out = (float*)d_out;

    dim3 grid(NDIM / BN, MDIM / BM);   // 86 x 8

    if (ws_size >= (size_t)MDIM * KDIM * 2) {
        _Float16* xi = (_Float16*)d_ws;
        xconv<<<4096, 256, 0, stream>>>(x, xi);
        awq_gemm<true><<<grid, 512, 0, stream>>>(x, xi, qw, qz, sc, out);
    } else {
        awq_gemm<false><<<grid, 512, 0, stream>>>(x, (const _Float16*)nullptr, qw, qz, sc, out);
    }
}